// Round 6
// baseline (1441.776 us; speedup 1.0000x reference)
//
#include <hip/hip_runtime.h>
#include <hip/hip_bf16.h>
#include <stdint.h>

#define E_ 4
#define T_ 4096
#define D_ 2048
#define H_ 8192

typedef __attribute__((ext_vector_type(8))) short bf16x8;
typedef __attribute__((ext_vector_type(4))) float f32x4;
typedef __attribute__((ext_vector_type(16))) float f32x16;
typedef __attribute__((ext_vector_type(4))) unsigned short u16x4;

// round-to-nearest-even f32 -> bf16 bit pattern
__device__ __forceinline__ unsigned short f2bf(float f) {
    unsigned int u = __float_as_uint(f);
    u = u + 0x7fffu + ((u >> 16) & 1u);
    return (unsigned short)(u >> 16);
}

// async global->LDS, 16B per lane. LDS dest is wave-uniform base; HW adds lane*16.
__device__ __forceinline__ void async16(const unsigned short* g, unsigned short* l) {
    auto gp = (const __attribute__((address_space(1))) unsigned int*)g;
    auto lp = (__attribute__((address_space(3))) unsigned int*)l;
    __builtin_amdgcn_global_load_lds(gp, lp, 16 /*bytes*/, 0 /*offset*/, 0 /*aux*/);
}

__device__ __forceinline__ f32x16 mfma32(bf16x8 a, bf16x8 b, f32x16 c) {
    return __builtin_amdgcn_mfma_f32_32x32x16_bf16(a, b, c, 0, 0, 0);
}

// ---------------- x: f32 -> bf16 (vectorized) ----------------
__global__ void cvt_x_kernel(const float4* __restrict__ in, uint2* __restrict__ out, long n4) {
    long i = (long)blockIdx.x * blockDim.x + threadIdx.x;
    long stride = (long)gridDim.x * blockDim.x;
    for (; i < n4; i += stride) {
        float4 v = in[i];
        uint2 o;
        o.x = (unsigned)f2bf(v.x) | ((unsigned)f2bf(v.y) << 16);
        o.y = (unsigned)f2bf(v.z) | ((unsigned)f2bf(v.w) << 16);
        out[i] = o;
    }
}

// ---------------- W (R x C, f32, row-major) -> Wt (C x R, bf16) per expert ----------------
__global__ void transpose_cvt_kernel(const float* __restrict__ W, unsigned short* __restrict__ Wt,
                                     int R, int C) {
    __shared__ float tile[64][65];
    const float* Wp = W + (size_t)blockIdx.z * R * C;
    unsigned short* Wtp = Wt + (size_t)blockIdx.z * R * C;
    const int c0 = blockIdx.x * 64, r0 = blockIdx.y * 64;
    const int tc = threadIdx.x & 63;
    const int tr = threadIdx.x >> 6; // 0..3
#pragma unroll
    for (int i = 0; i < 16; ++i) {
        int r = tr * 16 + i;
        tile[r][tc] = Wp[(size_t)(r0 + r) * C + c0 + tc];
    }
    __syncthreads();
#pragma unroll
    for (int i = 0; i < 16; ++i) {
        int r = tr * 16 + i;
        Wtp[(size_t)(c0 + r) * R + r0 + tc] = f2bf(tile[tc][r]);
    }
}

// ---------------- 256x256 GEMM: C[M][N] = A[M][K] * Bt[N][K]^T (+bias) ----------------
// 8 waves (2M x 4N), per-wave 128x64 output = acc f32x16[4 mb][2 nb] of 32x32 frags. BK=64.
// LDS: 2 dbuf x {A,B} x 2 halves x [128][64] bf16 = 128 KiB. XOR swizzle: stored element
// (row, 8g) holds logical k-group g ^ (row&7) (conflict-free, SQ_LDS_BANK_CONFLICT == 0).
// K-loop = r3/r5 2-barrier schedule (validated). This round: 32x32x16 MFMA (higher µbench
// ceiling, 2x fewer insts) + unroll-2 (compile-time slot) + immediate-folded ds addressing
// (8 precomputed swizzled base ptrs) + incrementally-bumped global staging ptrs.
// Fragment layouts (32x32x16_bf16): A/B: row/col = lane&31, k = (lane>>5)*8 + e.
// C/D (m74/m101-verified): col = lane&31, row = (reg&3) + 8*(reg>>2) + 4*(lane>>5).
template <int K, int OUT_MODE>
__global__ __launch_bounds__(512, 2) void gemm256_kernel(
    const unsigned short* __restrict__ A,   // [E][M][K]
    const unsigned short* __restrict__ Bt,  // [E][N][K]
    const float* __restrict__ bias,         // [E][N]
    void* __restrict__ Cout,                // [E][M][N]
    int M, int N)
{
    constexpr int BK = 64;
    constexpr int NT = K / BK;
    __shared__ __align__(16) unsigned short L[2][2][2][128][64]; // [dbuf][A/B][half][row][kel]

    // ---- XCD chunk + L3 supertile remap (r5-validated) ----------------------
    const int nx = gridDim.x, ny = gridDim.y;
    const int nwg = nx * ny * gridDim.z;
    const int w = (blockIdx.z * ny + blockIdx.y) * nx + blockIdx.x;
    const int cpx = nwg >> 3;
    const int xcd = w & 7;
    const int c = w >> 3;
    const int CR = cpx / nx;
    const int GX = (nx % 16 == 0) ? 16 : nx;
    const int g = c / (GX * CR);
    const int r1 = c - g * (GX * CR);
    const int byl = r1 / GX;
    const int bxi = r1 - byl * GX;
    const int fy = xcd * CR + byl;
    const int bx = g * GX + bxi;
    const int e = fy / ny;
    const int by = fy - e * ny;

    const unsigned short* Ae = A + (size_t)e * M * K;
    const unsigned short* Be = Bt + (size_t)e * N * K;
    const int bm0 = by * 256;
    const int bn0 = bx * 256;

    const int tid = threadIdx.x;
    const int lane = tid & 63;
    const int wid = tid >> 6;     // 0..7
    const int wr = wid >> 2;      // 0..1 (M half)
    const int wc = wid & 3;       // 0..3 (N quarter)

    // ---- staging geometry (r5-validated): per (half h, i), rows wid*16 + i*8 + (lane>>3)
    const int srow = wid * 16 + (lane >> 3);
    const int skel = 8 * ((lane & 7) ^ (lane >> 3)); // pre-swizzled global k offset

    // 8 incrementally-bumped global source pointers (start at k0 = 0)
    const unsigned short* gA00 = Ae + (size_t)(bm0 +   0 + srow + 0) * K + skel;
    const unsigned short* gA01 = Ae + (size_t)(bm0 +   0 + srow + 8) * K + skel;
    const unsigned short* gA10 = Ae + (size_t)(bm0 + 128 + srow + 0) * K + skel;
    const unsigned short* gA11 = Ae + (size_t)(bm0 + 128 + srow + 8) * K + skel;
    const unsigned short* gB00 = Be + (size_t)(bn0 +   0 + srow + 0) * K + skel;
    const unsigned short* gB01 = Be + (size_t)(bn0 +   0 + srow + 8) * K + skel;
    const unsigned short* gB10 = Be + (size_t)(bn0 + 128 + srow + 0) * K + skel;
    const unsigned short* gB11 = Be + (size_t)(bn0 + 128 + srow + 8) * K + skel;

#define STAGE_ALL(S_) do {                                   \
        async16(gB00, &L[S_][1][0][wid * 16 + 0][0]);        \
        async16(gB01, &L[S_][1][0][wid * 16 + 8][0]);        \
        async16(gB10, &L[S_][1][1][wid * 16 + 0][0]);        \
        async16(gB11, &L[S_][1][1][wid * 16 + 8][0]);        \
        async16(gA00, &L[S_][0][0][wid * 16 + 0][0]);        \
        async16(gA01, &L[S_][0][0][wid * 16 + 8][0]);        \
        async16(gA10, &L[S_][0][1][wid * 16 + 0][0]);        \
        async16(gA11, &L[S_][0][1][wid * 16 + 8][0]);        \
    } while (0)

#define BUMP_ALL() do {                                      \
        gA00 += BK; gA01 += BK; gA10 += BK; gA11 += BK;      \
        gB00 += BK; gB01 += BK; gB10 += BK; gB11 += BK;      \
    } while (0)

    // ---- fragment-read geometry (32x32 frags) -------------------------------
    // logical: row R = rbase + r5, k = ks*16 + kh*8 + e. stored col-group = kgroup ^ (R&7),
    // kgroup = ks*2 + kh. lane offset (elements) = r5*64 + (8*(kh^q)) ^ (ks*16), q = lane&7.
    const int r5 = lane & 31;
    const int kh = lane >> 5;
    const int q  = lane & 7;
    const int g0e = 8 * (kh ^ q);
    const unsigned short* Lp = &L[0][0][0][0][0];
    const unsigned short* pk[2][4];
#pragma unroll
    for (int s = 0; s < 2; ++s)
#pragma unroll
        for (int ks = 0; ks < 4; ++ks)
            pk[s][ks] = Lp + s * 32768 + r5 * 64 + (g0e ^ (ks * 16));

    // element-offset constants (fold into ds offset immediates; all <= 61440 B)
    const int AOFF = wr * 8192;                                   // + mb*2048
    const int BOFF = 16384 + (wc >> 1) * 8192 + (wc & 1) * 4096;  // + nb*2048

    f32x16 acc[4][2] = {};

    // ---- prologue: stage tile 0 fully, then tile 1 (order matters for vmcnt counting)
    STAGE_ALL(0);
    BUMP_ALL();
    STAGE_ALL(1);
    BUMP_ALL();

    bf16x8 a[2][4], b[2][4];

#define BODY(T_, S_) do {                                                              \
        if ((T_) == NT - 1) asm volatile("s_waitcnt vmcnt(0)" ::: "memory");           \
        else                asm volatile("s_waitcnt vmcnt(8)" ::: "memory");           \
        __builtin_amdgcn_s_barrier();                                                  \
        _Pragma("unroll")                                                              \
        for (int nb = 0; nb < 2; ++nb)                                                 \
            _Pragma("unroll")                                                          \
            for (int ks = 0; ks < 4; ++ks)                                             \
                b[nb][ks] = *(const bf16x8*)(pk[S_][ks] + BOFF + nb * 2048);           \
        _Pragma("unroll")                                                              \
        for (int mb = 0; mb < 2; ++mb)                                                 \
            _Pragma("unroll")                                                          \
            for (int ks = 0; ks < 4; ++ks)                                             \
                a[mb][ks] = *(const bf16x8*)(pk[S_][ks] + AOFF + mb * 2048);           \
        __builtin_amdgcn_s_setprio(1);                                                 \
        _Pragma("unroll")                                                              \
        for (int mb = 0; mb < 2; ++mb)                                                 \
            _Pragma("unroll")                                                          \
            for (int nb = 0; nb < 2; ++nb)                                             \
                _Pragma("unroll")                                                      \
                for (int ks = 0; ks < 4; ++ks)                                         \
                    acc[mb][nb] = mfma32(a[mb][ks], b[nb][ks], acc[mb][nb]);           \
        __builtin_amdgcn_s_setprio(0);                                                 \
        _Pragma("unroll")                                                              \
        for (int mb = 0; mb < 2; ++mb)                                                 \
            _Pragma("unroll")                                                          \
            for (int ks = 0; ks < 4; ++ks)                                             \
                a[mb][ks] = *(const bf16x8*)(pk[S_][ks] + AOFF + (mb + 2) * 2048);     \
        asm volatile("s_waitcnt lgkmcnt(0)" ::: "memory");                             \
        __builtin_amdgcn_sched_barrier(0);                                             \
        __builtin_amdgcn_s_barrier();                                                  \
        if ((T_) + 2 < NT) { STAGE_ALL(S_); }                                          \
        __builtin_amdgcn_sched_barrier(0);                                             \
        __builtin_amdgcn_s_setprio(1);                                                 \
        _Pragma("unroll")                                                              \
        for (int mb = 0; mb < 2; ++mb)                                                 \
            _Pragma("unroll")                                                          \
            for (int nb = 0; nb < 2; ++nb)                                             \
                _Pragma("unroll")                                                      \
                for (int ks = 0; ks < 4; ++ks)                                         \
                    acc[mb + 2][nb] = mfma32(a[mb][ks], b[nb][ks], acc[mb + 2][nb]);   \
        __builtin_amdgcn_s_setprio(0);                                                 \
        BUMP_ALL();                                                                    \
    } while (0)

    for (int t = 0; t < NT; t += 2) {
        BODY(t, 0);
        BODY(t + 1, 1);
    }
#undef BODY
#undef STAGE_ALL
#undef BUMP_ALL

    // ---- epilogue: LDS-transpose to contiguous row stores (r5-validated structure) ----
    // 32x32 C/D: col = lane&31, row-in-frag = (reg&3) + 8*(reg>>2) + 4*(lane>>5).
    // Stripe sg (32 rows) written by the 4 waves with wr == sg>>2, frag mb = sg&3.
    constexpr int ST = 260;
    float* S = (float*)&L[0][0][0][0][0];
    const float* bp = bias + (size_t)e * N;
    const float4 bb4 = *(const float4*)(bp + bn0 + lane * 4);
    const int c5 = lane & 31;
    const int hi = lane >> 5;

    unsigned short* Y = (unsigned short*)Cout + (size_t)e * M * N;
    float* O = (float*)Cout + (size_t)e * M * N;

#pragma unroll
    for (int sg = 0; sg < 8; ++sg) {
        __syncthreads();
        if (wr == (sg >> 2)) {
            const int mb = sg & 3;
#pragma unroll
            for (int nb = 0; nb < 2; ++nb) {
#pragma unroll
                for (int r = 0; r < 16; ++r) {
                    const int rf = (r & 3) + 8 * (r >> 2) + 4 * hi;
                    S[rf * ST + wc * 64 + nb * 32 + c5] = acc[mb][nb][r];
                }
            }
        }
        __syncthreads();
#pragma unroll
        for (int rr = 0; rr < 4; ++rr) {
            const int rl = wid * 4 + rr;
            const int rg = bm0 + sg * 32 + rl;
            f32x4 v = *(const f32x4*)&S[rl * ST + lane * 4];
            v[0] += bb4.x; v[1] += bb4.y; v[2] += bb4.z; v[3] += bb4.w;
            if (OUT_MODE == 0) {
                u16x4 o;
                o[0] = f2bf(fmaxf(v[0], 0.0f));
                o[1] = f2bf(fmaxf(v[1], 0.0f));
                o[2] = f2bf(fmaxf(v[2], 0.0f));
                o[3] = f2bf(fmaxf(v[3], 0.0f));
                *(u16x4*)(Y + (size_t)rg * N + bn0 + lane * 4) = o;
            } else {
                *(f32x4*)(O + (size_t)rg * N + bn0 + lane * 4) = v;
            }
        }
    }
}

extern "C" void kernel_launch(void* const* d_in, const int* in_sizes, int n_in,
                              void* d_out, int out_size, void* d_ws, size_t ws_size,
                              hipStream_t stream) {
    const float* x     = (const float*)d_in[0]; // (E,T,D)
    const float* fc1_w = (const float*)d_in[1]; // (E,D,H)
    const float* fc1_b = (const float*)d_in[2]; // (E,1,H)
    const float* fc2_w = (const float*)d_in[3]; // (E,H,D)
    const float* fc2_b = (const float*)d_in[4]; // (E,1,D)
    float* out = (float*)d_out;

    const size_t n_x  = (size_t)E_ * T_ * D_;
    const size_t n_w1 = (size_t)E_ * D_ * H_;
    const size_t n_w2 = (size_t)E_ * H_ * D_;
    const size_t n_y1 = (size_t)E_ * T_ * H_;

    const size_t need = (n_x + n_w1 + n_w2 + n_y1) * sizeof(unsigned short);
    if (ws_size < need) return;

    unsigned short* xb  = (unsigned short*)d_ws;
    unsigned short* w1t = xb + n_x;    // (E,H,D)
    unsigned short* w2t = w1t + n_w1;  // (E,D,H)
    unsigned short* y1  = w2t + n_w2;  // (E,T,H)

    cvt_x_kernel<<<2048, 256, 0, stream>>>((const float4*)x, (uint2*)xb, (long)(n_x / 4));
    {
        dim3 g(H_ / 64, D_ / 64, E_);
        transpose_cvt_kernel<<<g, 256, 0, stream>>>(fc1_w, w1t, D_, H_);
    }
    {
        dim3 g(D_ / 64, H_ / 64, E_);
        transpose_cvt_kernel<<<g, 256, 0, stream>>>(fc2_w, w2t, H_, D_);
    }
    // GEMM1: y1 = relu(x @ W1 + b1), bf16 out. M=T, N=H, K=D
    {
        dim3 g(H_ / 256, T_ / 256, E_);
        gemm256_kernel<D_, 0><<<g, 512, 0, stream>>>(xb, w1t, fc1_b, (void*)y1, T_, H_);
    }
    // GEMM2: out = y1 @ W2 + b2, f32 out. M=T, N=D, K=H
    {
        dim3 g(D_ / 256, T_ / 256, E_);
        gemm256_kernel<H_, 1><<<g, 512, 0, stream>>>(y1, w2t, fc2_b, (void*)out, T_, D_);
    }
}